// Round 8
// baseline (444.290 us; speedup 1.0000x reference)
//
#include <hip/hip_runtime.h>
#include <cstddef>
#include <cstdint>

#define B_DIM 8
#define T_SEQ 4096
#define C_DIM 768
#define M_ROWS (B_DIM * T_SEQ)   // 32768
#define CC (C_DIM * C_DIM)       // 589824
#define NCH 32
#define CHL (T_SEQ / NCH)        // 128

using bf16x8 = __attribute__((ext_vector_type(8))) short;
using f32x4  = __attribute__((ext_vector_type(4))) float;

static __device__ __forceinline__ unsigned short f2bf(float f) {
  unsigned int u = __float_as_uint(f);
  return (unsigned short)((u + 0x7fffu + ((u >> 16) & 1u)) >> 16);
}
static __device__ __forceinline__ float bf2f(unsigned short s) {
  return __uint_as_float(((unsigned int)s) << 16);
}

static __device__ __forceinline__ void gload_lds16(const void* g, void* l) {
  __builtin_amdgcn_global_load_lds(
      (const __attribute__((address_space(1))) unsigned int*)g,
      (__attribute__((address_space(3))) unsigned int*)l, 16, 0, 0);
}

// ---------------------------------------------------------------------------
// f32 -> bf16 converts.
// ---------------------------------------------------------------------------
__global__ __launch_bounds__(256) void convert_x(
    const float4* __restrict__ x, ushort4* __restrict__ xh)
{
  int i = blockIdx.x * 256 + threadIdx.x;
  float4 v = x[i];
  ushort4 h;
  h.x = f2bf(v.x); h.y = f2bf(v.y); h.z = f2bf(v.z); h.w = f2bf(v.w);
  xh[i] = h;
}

__global__ __launch_bounds__(256) void convert_w4(
    const float4* __restrict__ w0, const float4* __restrict__ w1,
    const float4* __restrict__ w2, const float4* __restrict__ w3,
    ushort4* __restrict__ dst)
{
  const int z = blockIdx.y;
  const float4* __restrict__ src = (z == 0) ? w0 : (z == 1) ? w1 : (z == 2) ? w2 : w3;
  int i = blockIdx.x * 256 + threadIdx.x;
  float4 v = src[i];
  ushort4 h;
  h.x = f2bf(v.x); h.y = f2bf(v.y); h.z = f2bf(v.z); h.w = f2bf(v.w);
  dst[(size_t)z * (CC / 4) + i] = h;
}

// ---------------------------------------------------------------------------
// Reg-B MFMA GEMM (NT): O[m,n] = sum_k A[m,k]*W[n,k], K=768, tile 256x256,
// BK=64 (12 K-tiles), 8 waves (2M x 4N), per-wave 128x64 out.
// A: LDS 96KB = 3 bufs x 32KB, staged via global_load_lds (lag 2 tiles).
//    buf layout: kh*16KB + q*4KB + row*16B  (q = k-chunk of 8) -> conflict-free
//    ds_read_b128; DMA dst wave-uniform + lane*16.
// B: NO LDS. Per-lane global_load_dwordx4 of W rows (L2-resident), ping-pong
//    registers (2x8 frags = 64 VGPR), prefetched one K-tile ahead.
// Sync: ONE vmcnt(4) + ONE s_barrier per K-tile. FIFO: tile t issues
//    B(t+1)x8 then A-DMA(t+2)x4; at tile t+1, vmcnt(4) drains B(t+1)+older
//    (incl. A(t+1)), leaves A(t+2)x4 in flight. Last tile: vmcnt(0).
// Sub-phase: 4x ds_read_b128 -> lgkmcnt(0) -> sched_barrier -> 16 MFMA
//    wrapped in setprio (rule #18 fence included).
// MODE 0: fused kvr, N=2304 over [Wk|Wv|Wr]; bf16 outs K/V/sigmoid->SR.
// MODE 1: out-GEMM, N=768, f32 out.
// ---------------------------------------------------------------------------
#define LOADB(DST, T) do { if ((T) < 12) {                                 \
    _Pragma("unroll")                                                      \
    for (int kh_ = 0; kh_ < 2; ++kh_) {                                    \
      _Pragma("unroll")                                                    \
      for (int ni_ = 0; ni_ < 4; ++ni_)                                    \
        DST[kh_][ni_] = *(const bf16x8*)(pB[ni_] + (T) * 64 + kh_ * 32);   \
    }                                                                      \
  } } while (0)

#define STAGEA(T) do { if ((T) < 12) {                                     \
    short* d0_ = lds + ((T) % 3) * 16384 + wave * 2048;                    \
    const int ko_ = (T) * 64;                                              \
    gload_lds16(pA0 + ko_, d0_);                                           \
    gload_lds16(pA1 + ko_, d0_ + 512);                                     \
    gload_lds16(pA2 + ko_, d0_ + 1024);                                    \
    gload_lds16(pA3 + ko_, d0_ + 1536);                                    \
  } } while (0)

#define SUBPH(T, KH, MQ, CUR)                                              \
  {                                                                        \
    const short* ab_ = lds + ((T) % 3) * 16384 + (KH) * 8192 + ard + (MQ) * 512; \
    bf16x8 a0_ = *(const bf16x8*)(ab_);                                    \
    bf16x8 a1_ = *(const bf16x8*)(ab_ + 128);                              \
    bf16x8 a2_ = *(const bf16x8*)(ab_ + 256);                              \
    bf16x8 a3_ = *(const bf16x8*)(ab_ + 384);                              \
    asm volatile("s_waitcnt lgkmcnt(0)" ::: "memory");                     \
    __builtin_amdgcn_sched_barrier(0);                                     \
    __builtin_amdgcn_s_setprio(1);                                         \
    _Pragma("unroll")                                                      \
    for (int ni_ = 0; ni_ < 4; ++ni_) {                                    \
      acc[(MQ)*4+0][ni_] = __builtin_amdgcn_mfma_f32_16x16x32_bf16(        \
          a0_, CUR[KH][ni_], acc[(MQ)*4+0][ni_], 0, 0, 0);                 \
      acc[(MQ)*4+1][ni_] = __builtin_amdgcn_mfma_f32_16x16x32_bf16(        \
          a1_, CUR[KH][ni_], acc[(MQ)*4+1][ni_], 0, 0, 0);                 \
      acc[(MQ)*4+2][ni_] = __builtin_amdgcn_mfma_f32_16x16x32_bf16(        \
          a2_, CUR[KH][ni_], acc[(MQ)*4+2][ni_], 0, 0, 0);                 \
      acc[(MQ)*4+3][ni_] = __builtin_amdgcn_mfma_f32_16x16x32_bf16(        \
          a3_, CUR[KH][ni_], acc[(MQ)*4+3][ni_], 0, 0, 0);                 \
    }                                                                      \
    __builtin_amdgcn_s_setprio(0);                                         \
  }

#define TILE(T, CUR, NXT, LAST)                                            \
  {                                                                        \
    if (LAST) { asm volatile("s_waitcnt vmcnt(0)" ::: "memory"); }         \
    else      { asm volatile("s_waitcnt vmcnt(4)" ::: "memory"); }         \
    __builtin_amdgcn_s_barrier();                                          \
    __builtin_amdgcn_sched_barrier(0);                                     \
    LOADB(NXT, (T) + 1);                                                   \
    STAGEA((T) + 2);                                                       \
    __builtin_amdgcn_sched_barrier(0);                                     \
    SUBPH(T, 0, 0, CUR) SUBPH(T, 0, 1, CUR)                                \
    SUBPH(T, 1, 0, CUR) SUBPH(T, 1, 1, CUR)                                \
  }

template<int MODE>
__global__ __launch_bounds__(512, 2) void gemmRB(
    const short* __restrict__ A, const short* __restrict__ Wb,
    unsigned short* __restrict__ OK, unsigned short* __restrict__ OV,
    unsigned short* __restrict__ OSR, float* __restrict__ Oout)
{
  extern __shared__ short lds[];   // 96 KB
  const int K = C_DIM;
  constexpr int NWN = (MODE == 0) ? 9 : 3;     // n-tiles of 256
  constexpr int CPX = (MODE == 0) ? 144 : 48;  // blocks per XCD (bijective)

  int f  = blockIdx.x + blockIdx.y * NWN;
  int wg = (f & 7) * CPX + (f >> 3);
  const int n0 = (wg % NWN) * 256;
  const int m0 = (wg / NWN) * 256;

  const int tid  = threadIdx.x;
  const int lane = tid & 63, wave = tid >> 6;
  const int wr = wave >> 2, wc = wave & 3;   // 2M x 4N wave grid
  const int lr = lane & 15, lk = lane >> 4;

  // A-frag ds_read base (shorts): q(=lk)*2048 + (wr*128 + lr)*8
  const int ard = lk * 2048 + (wr * 128 + lr) * 8;

  // A staging sources: slot w4l = wave*4+l; row=(w4l&3)*64+lane,
  // q=(w4l>>2)&3, kh=w4l>>4.  src = A + (m0+row)*K + kh*32 + q*8 (+t*64)
  const int w4l = wave * 4;
  const short* pA0 = A + (size_t)(m0 + ((w4l + 0) & 3) * 64 + lane) * K
                     + ((w4l + 0) >> 4) * 32 + (((w4l + 0) >> 2) & 3) * 8;
  const short* pA1 = A + (size_t)(m0 + ((w4l + 1) & 3) * 64 + lane) * K
                     + ((w4l + 1) >> 4) * 32 + (((w4l + 1) >> 2) & 3) * 8;
  const short* pA2 = A + (size_t)(m0 + ((w4l + 2) & 3) * 64 + lane) * K
                     + ((w4l + 2) >> 4) * 32 + (((w4l + 2) >> 2) & 3) * 8;
  const short* pA3 = A + (size_t)(m0 + ((w4l + 3) & 3) * 64 + lane) * K
                     + ((w4l + 3) >> 4) * 32 + (((w4l + 3) >> 2) & 3) * 8;

  // B per-lane pointers: col = n0 + wc*64 + ni*16 + lr, k-base = lk*8
  const short* pB[4];
#pragma unroll
  for (int ni = 0; ni < 4; ++ni)
    pB[ni] = Wb + (size_t)(n0 + wc * 64 + ni * 16 + lr) * K + lk * 8;

  f32x4 acc[8][4];
#pragma unroll
  for (int i = 0; i < 8; ++i)
#pragma unroll
    for (int j = 0; j < 4; ++j) acc[i][j] = (f32x4){0.f, 0.f, 0.f, 0.f};

  bf16x8 bA[2][4], bB2[2][4];

  // Prologue: A(0), B(0), A(1) -> queue [A0 4, B0 8, A1 4]
  STAGEA(0);
  LOADB(bA, 0);
  STAGEA(1);

  // 12 K-tiles, ping-pong B buffers, 2 tiles per iteration.
  for (int it = 0; it < 6; ++it) {
    const int t0 = 2 * it;
    TILE(t0, bA, bB2, 0)
    TILE(t0 + 1, bB2, bA, (it == 5))
  }

  // Epilogue
  if (MODE == 0) {
    const int which = n0 / 768;               // 0:K 1:V 2:SR (all bf16 out)
    const int nc = (n0 % 768) + wc * 64;
    unsigned short* __restrict__ D = (which == 0) ? OK : (which == 1) ? OV : OSR;
#pragma unroll
    for (int mi = 0; mi < 8; ++mi)
#pragma unroll
      for (int ni = 0; ni < 4; ++ni) {
        const int row = m0 + wr * 128 + mi * 16 + lk * 4;
        const int col = nc + ni * 16 + lr;
#pragma unroll
        for (int j = 0; j < 4; ++j) {
          float v = acc[mi][ni][j];
          if (which == 2) v = 1.f / (1.f + __expf(-v));
          D[(size_t)(row + j) * C_DIM + col] = f2bf(v);
        }
      }
  } else {
#pragma unroll
    for (int mi = 0; mi < 8; ++mi)
#pragma unroll
      for (int ni = 0; ni < 4; ++ni) {
        const int row = m0 + wr * 128 + mi * 16 + lk * 4;
        const int col = n0 + wc * 64 + ni * 16 + lr;
#pragma unroll
        for (int j = 0; j < 4; ++j)
          Oout[(size_t)(row + j) * C_DIM + col] = acc[mi][ni][j];
      }
  }
}

// ---------------------------------------------------------------------------
// WKV chunk-parallel scan over bf16 K/V. Pass 1: per-(b,c,chunk) local
// transition triple (f32 state).
// ---------------------------------------------------------------------------
#define P1_LOAD(kk_, vv_, base_)                                  \
  _Pragma("unroll") for (int j = 0; j < 8; ++j) {                 \
    int r_ = si[(base_) + j];                                     \
    kk_[j] = Kb[(size_t)r_ * C_DIM];                              \
    vv_[j] = Vb[(size_t)r_ * C_DIM];                              \
  }
#define P1_COMP(kk_, vv_)                                         \
  _Pragma("unroll") for (int j = 0; j < 8; ++j) {                 \
    float kt = bf2f(kk_[j]), vt = bf2f(vv_[j]);                   \
    float ww2 = w + pp; float p2 = fmaxf(ww2, kt);                \
    float e1b = __expf(ww2 - p2), e2b = __expf(kt - p2);          \
    aa = e1b * aa + e2b * vt; bb = e1b * bb + e2b; pp = p2;       \
  }

__global__ __launch_bounds__(256) void wkv_pass1(
    const unsigned short* __restrict__ Kin, const unsigned short* __restrict__ Vin,
    const int* __restrict__ sidx, const float* __restrict__ decay,
    float* __restrict__ aL, float* __restrict__ bL, float* __restrict__ pL)
{
  __shared__ int si[CHL];
  const int tid = threadIdx.x;
  const int ch = blockIdx.x, b = blockIdx.z;
  const int c = blockIdx.y * 256 + tid;
  if (tid < CHL) si[tid] = sidx[ch * CHL + tid];
  __syncthreads();
  const float w = decay[c] * (1.0f / (float)T_SEQ);
  const unsigned short* Kb = Kin + (size_t)b * T_SEQ * C_DIM + c;
  const unsigned short* Vb = Vin + (size_t)b * T_SEQ * C_DIM + c;
  float aa = 0.f, bb = 0.f, pp = -1e38f;
  unsigned short kA[8], vA[8], kB[8], vB[8];
  P1_LOAD(kA, vA, 0)
  for (int t0 = 0; t0 < CHL; t0 += 16) {
    P1_LOAD(kB, vB, t0 + 8)
    P1_COMP(kA, vA)
    if (t0 + 16 < CHL) { P1_LOAD(kA, vA, t0 + 16) }
    P1_COMP(kB, vB)
  }
  const int idx = (b * C_DIM + c) * NCH + ch;
  aL[idx] = aa; bL[idx] = bb; pL[idx] = pp;
}

// Serial scan over chunks per (b,c).
__global__ __launch_bounds__(256) void wkv_scan(
    const float* __restrict__ aL, const float* __restrict__ bL,
    const float* __restrict__ pL,
    float* __restrict__ aI, float* __restrict__ bI, float* __restrict__ pI,
    const float* __restrict__ decay)
{
  const int g = blockIdx.x * 256 + threadIdx.x;  // 0..6143 = b*C + c
  const int c = g % C_DIM;
  const float wL = decay[c] * ((float)CHL / (float)T_SEQ);
  float aa = 0.f, bb = 0.f, pp = -1e38f;
  const int base = g * NCH;
  for (int ch = 0; ch < NCH; ++ch) {
    aI[base + ch] = aa; bI[base + ch] = bb; pI[base + ch] = pp;
    float p1 = pp + wL;
    float p2 = pL[base + ch];
    float p  = fmaxf(p1, p2);
    float e1 = __expf(p1 - p), e2 = __expf(p2 - p);
    aa = e1 * aa + e2 * aL[base + ch];
    bb = e1 * bb + e2 * bL[base + ch];
    pp = p;
  }
}

// Pass 2: replay chunk with incoming state; y (bf16) scattered to natural order.
#define P2_LOAD(rr_, kk_, vv_, base_)                             \
  _Pragma("unroll") for (int j = 0; j < 8; ++j) {                 \
    int r_ = si[(base_) + j];                                     \
    rr_[j] = r_;                                                  \
    kk_[j] = Kb[(size_t)r_ * C_DIM];                              \
    vv_[j] = Vb[(size_t)r_ * C_DIM];                              \
  }
#define P2_COMP(rr_, kk_, vv_)                                    \
  _Pragma("unroll") for (int j = 0; j < 8; ++j) {                 \
    float kt = bf2f(kk_[j]), vt = bf2f(vv_[j]);                   \
    float ww = u + kt; float p = fmaxf(pp, ww);                   \
    float e1 = __expf(pp - p), e2 = __expf(ww - p);               \
    float y = (e1 * aa + e2 * vt) / (e1 * bb + e2);               \
    Yb[(size_t)rr_[j] * C_DIM] = f2bf(y);                         \
    float ww2 = w + pp; float p2 = fmaxf(ww2, kt);                \
    float e1b = __expf(ww2 - p2), e2b = __expf(kt - p2);          \
    aa = e1b * aa + e2b * vt; bb = e1b * bb + e2b; pp = p2;       \
  }

__global__ __launch_bounds__(256) void wkv_pass2(
    const unsigned short* __restrict__ Kin, const unsigned short* __restrict__ Vin,
    const int* __restrict__ sidx,
    const float* __restrict__ decay, const float* __restrict__ first,
    const float* __restrict__ aI, const float* __restrict__ bI,
    const float* __restrict__ pI, unsigned short* __restrict__ Y)
{
  __shared__ int si[CHL];
  const int tid = threadIdx.x;
  const int ch = blockIdx.x, b = blockIdx.z;
  const int c = blockIdx.y * 256 + tid;
  if (tid < CHL) si[tid] = sidx[ch * CHL + tid];
  __syncthreads();
  const float w = decay[c] * (1.0f / (float)T_SEQ);
  const float u = first[c] * (1.0f / (float)T_SEQ);
  const unsigned short* Kb = Kin + (size_t)b * T_SEQ * C_DIM + c;
  const unsigned short* Vb = Vin + (size_t)b * T_SEQ * C_DIM + c;
  unsigned short* Yb = Y + (size_t)b * T_SEQ * C_DIM + c;
  const int idx = (b * C_DIM + c) * NCH + ch;
  float aa = aI[idx], bb = bI[idx], pp = pI[idx];
  int rA[8], rB[8]; unsigned short kA[8], vA[8], kB[8], vB[8];
  P2_LOAD(rA, kA, vA, 0)
  for (int t0 = 0; t0 < CHL; t0 += 16) {
    P2_LOAD(rB, kB, vB, t0 + 8)
    P2_COMP(rA, kA, vA)
    if (t0 + 16 < CHL) { P2_LOAD(rA, kA, vA, t0 + 16) }
    P2_COMP(rB, kB, vB)
  }
}

// ---------------------------------------------------------------------------
// Row LayerNorm over C + sigmoid gate; bf16 in (Y, SR), bf16 out (G).
// ---------------------------------------------------------------------------
__global__ __launch_bounds__(256) void ln_gate(
    const unsigned short* __restrict__ Y, const unsigned short* __restrict__ SR,
    const float* __restrict__ gam, const float* __restrict__ bet,
    unsigned short* __restrict__ G)
{
  const size_t row = blockIdx.x;
  const unsigned short* x = Y + row * C_DIM;
  const unsigned short* sr = SR + row * C_DIM;
  unsigned short* go = G + row * C_DIM;
  const int tid = threadIdx.x;

  float vals[3];
  float s = 0.f, s2 = 0.f;
#pragma unroll
  for (int j = 0; j < 3; ++j) {
    float v = bf2f(x[tid + j * 256]);
    vals[j] = v;
    s += v; s2 += v * v;
  }
#pragma unroll
  for (int off = 32; off >= 1; off >>= 1) {
    s  += __shfl_xor(s, off, 64);
    s2 += __shfl_xor(s2, off, 64);
  }
  __shared__ float red[8];
  const int wid = tid >> 6;
  if ((tid & 63) == 0) { red[wid] = s; red[wid + 4] = s2; }
  __syncthreads();
  s  = red[0] + red[1] + red[2] + red[3];
  s2 = red[4] + red[5] + red[6] + red[7];

  const float mu   = s * (1.f / (float)C_DIM);
  const float var  = s2 * (1.f / (float)C_DIM) - mu * mu;
  const float rsig = rsqrtf(var + 1e-5f);

#pragma unroll
  for (int j = 0; j < 3; ++j) {
    const int cc = tid + j * 256;
    float yv = (vals[j] - mu) * rsig * gam[cc] + bet[cc];
    go[cc] = f2bf(yv * bf2f(sr[cc]));
  }
}

// ---------------------------------------------------------------------------
extern "C" void kernel_launch(void* const* d_in, const int* in_sizes, int n_in,
                              void* d_out, int out_size, void* d_ws, size_t ws_size,
                              hipStream_t stream) {
  const float* x     = (const float*)d_in[0];
  const int*   sidx  = (const int*)  d_in[1];
  const float* decay = (const float*)d_in[2];
  const float* first = (const float*)d_in[3];
  const float* Wk    = (const float*)d_in[4];
  const float* Wv    = (const float*)d_in[5];
  const float* Wr    = (const float*)d_in[6];
  const float* Wo    = (const float*)d_in[7];
  const float* ln_g  = (const float*)d_in[8];
  const float* ln_b  = (const float*)d_in[9];
  float* out = (float*)d_out;

  const size_t NE = (size_t)M_ROWS * C_DIM;  // 25165824
  // Workspace layout (~210 MB):
  short* Whs  = (short*)d_ws;                        // 4*CC bf16 [Wk|Wv|Wr|Wo]
  short* x_hi = Whs + 4 * (size_t)CC;                // NE bf16
  unsigned short* Ybuf = (unsigned short*)x_hi;      // alias: Y after kvr done
  unsigned short* Kbuf = (unsigned short*)(x_hi + NE);  // NE bf16
  unsigned short* Gbuf = Kbuf;                       // alias: after K dead
  unsigned short* Vbuf = Kbuf + NE;                  // NE bf16
  unsigned short* SRb  = Vbuf + NE;                  // NE bf16
  float* aL = (float*)(SRb + NE);                    // 6 x 196608 f32
  float* bL = aL + 196608;
  float* pL = bL + 196608;
  float* aI = pL + 196608;
  float* bI = aI + 196608;
  float* pI = bI + 196608;

  // Allow 96 KB dynamic LDS (idempotent, capture-safe).
  (void)hipFuncSetAttribute(reinterpret_cast<const void*>(&gemmRB<0>),
                            hipFuncAttributeMaxDynamicSharedMemorySize, 98304);
  (void)hipFuncSetAttribute(reinterpret_cast<const void*>(&gemmRB<1>),
                            hipFuncAttributeMaxDynamicSharedMemorySize, 98304);

  // 1) bf16 conversions
  convert_x<<<24576, 256, 0, stream>>>((const float4*)x, (ushort4*)x_hi);
  convert_w4<<<dim3(576, 4), 256, 0, stream>>>(
      (const float4*)Wk, (const float4*)Wv, (const float4*)Wr, (const float4*)Wo,
      (ushort4*)Whs);

  // 2) fused k|v|sr GEMM: M=32768, N=2304, K=768; all outputs bf16
  gemmRB<0><<<dim3(9, 128), 512, 98304, stream>>>(
      x_hi, Whs, Kbuf, Vbuf, SRb, nullptr);

  // 3) WKV: chunk transitions -> serial chunk scan -> replay with y output
  wkv_pass1<<<dim3(NCH, 3, B_DIM), 256, 0, stream>>>(Kbuf, Vbuf, sidx, decay, aL, bL, pL);
  wkv_scan<<<24, 256, 0, stream>>>(aL, bL, pL, aI, bI, pI, decay);
  wkv_pass2<<<dim3(NCH, 3, B_DIM), 256, 0, stream>>>(Kbuf, Vbuf, sidx, decay, first,
                                                     aI, bI, pI, Ybuf);
  // 4) LayerNorm + gate -> bf16 GEMM operand (G aliases K; K dead now)
  ln_gate<<<M_ROWS, 256, 0, stream>>>(Ybuf, SRb, ln_g, ln_b, Gbuf);
  // 5) out = G @ Wo^T (384 blocks of 256^2, f32 out)
  gemmRB<1><<<dim3(3, 128), 512, 98304, stream>>>(
      (const short*)Gbuf, Whs + 3 * (size_t)CC, nullptr, nullptr, nullptr, out);
}

// Round 9
// 317.195 us; speedup vs baseline: 1.4007x; 1.4007x over previous
//
#include <hip/hip_runtime.h>
#include <cstddef>
#include <cstdint>

#define B_DIM 8
#define T_SEQ 4096
#define C_DIM 768
#define M_ROWS (B_DIM * T_SEQ)   // 32768
#define CC (C_DIM * C_DIM)       // 589824
#define NCH 32
#define CHL (T_SEQ / NCH)        // 128

using bf16x8 = __attribute__((ext_vector_type(8))) short;
using f32x4  = __attribute__((ext_vector_type(4))) float;

static __device__ __forceinline__ unsigned short f2bf(float f) {
  unsigned int u = __float_as_uint(f);
  return (unsigned short)((u + 0x7fffu + ((u >> 16) & 1u)) >> 16);
}
static __device__ __forceinline__ float bf2f(unsigned short s) {
  return __uint_as_float(((unsigned int)s) << 16);
}

static __device__ __forceinline__ void gload_lds16(const void* g, void* l) {
  __builtin_amdgcn_global_load_lds(
      (const __attribute__((address_space(1))) unsigned int*)g,
      (__attribute__((address_space(3))) unsigned int*)l, 16, 0, 0);
}

// ---------------------------------------------------------------------------
// f32 -> bf16 converts.
// ---------------------------------------------------------------------------
__global__ __launch_bounds__(256) void convert_x(
    const float4* __restrict__ x, ushort4* __restrict__ xh)
{
  int i = blockIdx.x * 256 + threadIdx.x;
  float4 v = x[i];
  ushort4 h;
  h.x = f2bf(v.x); h.y = f2bf(v.y); h.z = f2bf(v.z); h.w = f2bf(v.w);
  xh[i] = h;
}

__global__ __launch_bounds__(256) void convert_w4(
    const float4* __restrict__ w0, const float4* __restrict__ w1,
    const float4* __restrict__ w2, const float4* __restrict__ w3,
    ushort4* __restrict__ dst)
{
  const int z = blockIdx.y;
  const float4* __restrict__ src = (z == 0) ? w0 : (z == 1) ? w1 : (z == 2) ? w2 : w3;
  int i = blockIdx.x * 256 + threadIdx.x;
  float4 v = src[i];
  ushort4 h;
  h.x = f2bf(v.x); h.y = f2bf(v.y); h.z = f2bf(v.z); h.w = f2bf(v.w);
  dst[(size_t)z * (CC / 4) + i] = h;
}

// ---------------------------------------------------------------------------
// 8-phase 256x256 MFMA GEMM (NT), K=768, BK=64, 8 waves (2M x 4N),
// per-wave 128x64 out, 16x16x32 bf16 MFMA. R7 schedule EXACTLY (stage slots,
// vmcnt(4)@P3/P7, guards) — only staging addressing + LDS layout changed:
//  * 4 lanes per row, 64B contiguous global per row -> full-sector coalescing
//    (was 1 lane/row = 4x L2 sector overfetch, the measured bottleneck).
//  * LDS per (kh,h) 8KB region: row-major 64B/row, 16B-chunk swizzle
//    s = kq ^ ((row>>1)&3); inverse swizzle applied to GLOBAL source
//    (rule #21: both-sides-or-neither). b128 reads hit the wave64 8-cycle
//    bank floor (uniform); swizzle is lane-constant: lk ^ ((lr>>1)&3).
// MODE 0: fused kvr, N=2304 over [Wk|Wv|Wr]; bf16 outs K/V/sigmoid->SR.
// MODE 1: out-GEMM, N=768, f32 out.
// ---------------------------------------------------------------------------
// STG: 2 instrs (h=0,1); dest base DB + KH*16384 + wave*1024 (+8192 for h1).
#define STG_A(DB, TAU, KH) do {                                            \
    const int ko_ = (TAU) * 64 + (KH) * 32;                                \
    short* d_ = lds + (((DB) + (KH) * 16384 + wave * 1024) >> 1);          \
    gload_lds16(pA_h0 + ko_, d_);                                          \
    gload_lds16(pA_h1 + ko_, d_ + 4096);                                   \
  } while (0)
#define STG_B(DB, TAU, KH) do {                                            \
    const int ko_ = (TAU) * 64 + (KH) * 32;                                \
    short* d_ = lds + (((DB) + 32768 + (KH) * 16384 + wave * 1024) >> 1);  \
    gload_lds16(pW_h0 + ko_, d_);                                          \
    gload_lds16(pW_h1 + ko_, d_ + 4096);                                   \
  } while (0)

#define PHASE(DB, KH, MQ, READB, STAGE, CKPT)                              \
  {                                                                        \
    _Pragma("unroll")                                                      \
    for (int mi = 0; mi < 4; ++mi)                                         \
      a[mi] = *(const bf16x8*)(lds +                                       \
          (((DB) + (KH) * 16384 + aoff + (MQ) * 4096 + mi * 1024) >> 1));  \
    if (READB) {                                                           \
      _Pragma("unroll")                                                    \
      for (int ni = 0; ni < 4; ++ni)                                       \
        b[ni] = *(const bf16x8*)(lds +                                     \
            (((DB) + 32768 + (KH) * 16384 + boff + ni * 1024) >> 1));      \
    }                                                                      \
    STAGE;                                                                 \
    __builtin_amdgcn_s_barrier();                                          \
    asm volatile("s_waitcnt lgkmcnt(0)" ::: "memory");                     \
    __builtin_amdgcn_sched_barrier(0);                                     \
    __builtin_amdgcn_s_setprio(1);                                         \
    _Pragma("unroll")                                                      \
    for (int mi = 0; mi < 4; ++mi)                                         \
      _Pragma("unroll")                                                    \
      for (int ni = 0; ni < 4; ++ni)                                       \
        acc[(MQ) * 4 + mi][ni] = __builtin_amdgcn_mfma_f32_16x16x32_bf16(  \
            a[mi], b[ni], acc[(MQ) * 4 + mi][ni], 0, 0, 0);                \
    __builtin_amdgcn_s_setprio(0);                                         \
    CKPT;                                                                  \
    __builtin_amdgcn_s_barrier();                                          \
  }

template<int MODE>
__global__ __launch_bounds__(512, 2) void gemm8p(
    const short* __restrict__ A, const short* __restrict__ Wb,
    unsigned short* __restrict__ OK, unsigned short* __restrict__ OV,
    unsigned short* __restrict__ OSR, float* __restrict__ Oout)
{
  extern __shared__ short lds[];   // 128 KB
  const int K = C_DIM;
  constexpr int NWN = (MODE == 0) ? 9 : 3;     // n-tiles
  constexpr int CPX = (MODE == 0) ? 144 : 48;  // blocks per XCD (bijective)

  int f  = blockIdx.x + blockIdx.y * NWN;
  int wg = (f & 7) * CPX + (f >> 3);
  const int n0 = (wg % NWN) * 256;
  const int m0 = (wg / NWN) * 256;

  const int tid  = threadIdx.x;
  const int lane = tid & 63, wave = tid >> 6;
  const int wr = wave >> 2, wc = wave & 3;   // 2M x 4N wave grid
  const int lr = lane & 15, lk = lane >> 4;

  // fragment swizzle (lane-constant): slot = lk ^ ((lr>>1)&3)
  const int aswz = lk ^ ((lr >> 1) & 3);
  // A frag byte offset within (DB,KH) region: wr*8192 + row127*64 + aswz*16
  const int aoff = wr * 8192 + lr * 64 + aswz * 16;
  // B frag: (wc>>1)*8192 + ((wc&1)*64 + ni*16 + lr)*64 + aswz*16
  const int boff = (wc >> 1) * 8192 + (wc & 1) * 4096 + lr * 64 + aswz * 16;

  // staging sources: 4 lanes per row, 64B contiguous (chunk-permuted).
  // row_local = wave*16 + (lane>>2); kq = (lane&3) ^ ((lane>>3)&3)
  const int srow = wave * 16 + (lane >> 2);
  const int skq  = (lane & 3) ^ ((lane >> 3) & 3);
  const short* pA_h0 = A + (size_t)(m0 + srow) * K + skq * 8;
  const short* pA_h1 = pA_h0 + (size_t)128 * K;
  const short* pW_h0 = Wb + (size_t)(n0 + srow) * K + skq * 8;
  const short* pW_h1 = pW_h0 + (size_t)128 * K;

  f32x4 acc[8][4];
#pragma unroll
  for (int i = 0; i < 8; ++i)
#pragma unroll
    for (int j = 0; j < 4; ++j) acc[i][j] = (f32x4){0.f, 0.f, 0.f, 0.f};

  // Prologue: stage tiles 0 (buf0) and 1 (buf1) fully; wait tile 0.
  STG_A(0, 0, 0); STG_B(0, 0, 0); STG_A(0, 0, 1); STG_B(0, 0, 1);
  STG_A(65536, 1, 0); STG_B(65536, 1, 0); STG_A(65536, 1, 1); STG_B(65536, 1, 1);
  asm volatile("s_waitcnt vmcnt(8)" ::: "memory");
  __builtin_amdgcn_s_barrier();

  bf16x8 a[4], b[4];
  // 12 K-tiles, 2 per iteration; stage lag per R7; vmcnt(4) at P3/P7.
  for (int it = 0; it < 6; ++it) {
    PHASE(0, 0, 0, 1, if (it >= 1) STG_A(65536, 2 * it + 1, 1), )
    PHASE(0, 0, 1, 0, if (it >= 1) STG_B(65536, 2 * it + 1, 1), )
    PHASE(0, 1, 0, 1, if (it < 5) STG_A(0, 2 * it + 2, 0), )
    PHASE(0, 1, 1, 0, if (it < 5) STG_B(0, 2 * it + 2, 0),
          if (it < 5) { asm volatile("s_waitcnt vmcnt(4)" ::: "memory"); }
          else       { asm volatile("s_waitcnt vmcnt(0)" ::: "memory"); })
    PHASE(65536, 0, 0, 1, if (it < 5) STG_A(0, 2 * it + 2, 1), )
    PHASE(65536, 0, 1, 0, if (it < 5) STG_B(0, 2 * it + 2, 1), )
    PHASE(65536, 1, 0, 1, if (it < 5) STG_A(65536, 2 * it + 3, 0), )
    PHASE(65536, 1, 1, 0, if (it < 5) STG_B(65536, 2 * it + 3, 0),
          if (it < 5) { asm volatile("s_waitcnt vmcnt(4)" ::: "memory"); })
  }

  // Epilogue (unchanged from R7)
  if (MODE == 0) {
    const int which = n0 / 768;               // 0:K 1:V 2:SR (all bf16 out)
    const int nc = (n0 % 768) + wc * 64;
    unsigned short* __restrict__ D = (which == 0) ? OK : (which == 1) ? OV : OSR;
#pragma unroll
    for (int mi = 0; mi < 8; ++mi)
#pragma unroll
      for (int ni = 0; ni < 4; ++ni) {
        const int row = m0 + wr * 128 + mi * 16 + lk * 4;
        const int col = nc + ni * 16 + lr;
#pragma unroll
        for (int j = 0; j < 4; ++j) {
          float v = acc[mi][ni][j];
          if (which == 2) v = 1.f / (1.f + __expf(-v));
          D[(size_t)(row + j) * C_DIM + col] = f2bf(v);
        }
      }
  } else {
#pragma unroll
    for (int mi = 0; mi < 8; ++mi)
#pragma unroll
      for (int ni = 0; ni < 4; ++ni) {
        const int row = m0 + wr * 128 + mi * 16 + lk * 4;
        const int col = n0 + wc * 64 + ni * 16 + lr;
#pragma unroll
        for (int j = 0; j < 4; ++j)
          Oout[(size_t)(row + j) * C_DIM + col] = acc[mi][ni][j];
      }
  }
}

// ---------------------------------------------------------------------------
// WKV chunk-parallel scan over bf16 K/V (unchanged from R7).
// ---------------------------------------------------------------------------
#define P1_LOAD(kk_, vv_, base_)                                  \
  _Pragma("unroll") for (int j = 0; j < 8; ++j) {                 \
    int r_ = si[(base_) + j];                                     \
    kk_[j] = Kb[(size_t)r_ * C_DIM];                              \
    vv_[j] = Vb[(size_t)r_ * C_DIM];                              \
  }
#define P1_COMP(kk_, vv_)                                         \
  _Pragma("unroll") for (int j = 0; j < 8; ++j) {                 \
    float kt = bf2f(kk_[j]), vt = bf2f(vv_[j]);                   \
    float ww2 = w + pp; float p2 = fmaxf(ww2, kt);                \
    float e1b = __expf(ww2 - p2), e2b = __expf(kt - p2);          \
    aa = e1b * aa + e2b * vt; bb = e1b * bb + e2b; pp = p2;       \
  }

__global__ __launch_bounds__(256) void wkv_pass1(
    const unsigned short* __restrict__ Kin, const unsigned short* __restrict__ Vin,
    const int* __restrict__ sidx, const float* __restrict__ decay,
    float* __restrict__ aL, float* __restrict__ bL, float* __restrict__ pL)
{
  __shared__ int si[CHL];
  const int tid = threadIdx.x;
  const int ch = blockIdx.x, b = blockIdx.z;
  const int c = blockIdx.y * 256 + tid;
  if (tid < CHL) si[tid] = sidx[ch * CHL + tid];
  __syncthreads();
  const float w = decay[c] * (1.0f / (float)T_SEQ);
  const unsigned short* Kb = Kin + (size_t)b * T_SEQ * C_DIM + c;
  const unsigned short* Vb = Vin + (size_t)b * T_SEQ * C_DIM + c;
  float aa = 0.f, bb = 0.f, pp = -1e38f;
  unsigned short kA[8], vA[8], kB[8], vB[8];
  P1_LOAD(kA, vA, 0)
  for (int t0 = 0; t0 < CHL; t0 += 16) {
    P1_LOAD(kB, vB, t0 + 8)
    P1_COMP(kA, vA)
    if (t0 + 16 < CHL) { P1_LOAD(kA, vA, t0 + 16) }
    P1_COMP(kB, vB)
  }
  const int idx = (b * C_DIM + c) * NCH + ch;
  aL[idx] = aa; bL[idx] = bb; pL[idx] = pp;
}

// Serial scan over chunks per (b,c).
__global__ __launch_bounds__(256) void wkv_scan(
    const float* __restrict__ aL, const float* __restrict__ bL,
    const float* __restrict__ pL,
    float* __restrict__ aI, float* __restrict__ bI, float* __restrict__ pI,
    const float* __restrict__ decay)
{
  const int g = blockIdx.x * 256 + threadIdx.x;  // 0..6143 = b*C + c
  const int c = g % C_DIM;
  const float wL = decay[c] * ((float)CHL / (float)T_SEQ);
  float aa = 0.f, bb = 0.f, pp = -1e38f;
  const int base = g * NCH;
  for (int ch = 0; ch < NCH; ++ch) {
    aI[base + ch] = aa; bI[base + ch] = bb; pI[base + ch] = pp;
    float p1 = pp + wL;
    float p2 = pL[base + ch];
    float p  = fmaxf(p1, p2);
    float e1 = __expf(p1 - p), e2 = __expf(p2 - p);
    aa = e1 * aa + e2 * aL[base + ch];
    bb = e1 * bb + e2 * bL[base + ch];
    pp = p;
  }
}

// Pass 2: replay chunk with incoming state; y (bf16) scattered to natural order.
#define P2_LOAD(rr_, kk_, vv_, base_)                             \
  _Pragma("unroll") for (int j = 0; j < 8; ++j) {                 \
    int r_ = si[(base_) + j];                                     \
    rr_[j] = r_;                                                  \
    kk_[j] = Kb[(size_t)r_ * C_DIM];                              \
    vv_[j] = Vb[(size_t)r_ * C_DIM];                              \
  }
#define P2_COMP(rr_, kk_, vv_)                                    \
  _Pragma("unroll") for (int j = 0; j < 8; ++j) {                 \
    float kt = bf2f(kk_[j]), vt = bf2f(vv_[j]);                   \
    float ww = u + kt; float p = fmaxf(pp, ww);                   \
    float e1 = __expf(pp - p), e2 = __expf(ww - p);               \
    float y = (e1 * aa + e2 * vt) / (e1 * bb + e2);               \
    Yb[(size_t)rr_[j] * C_DIM] = f2bf(y);                         \
    float ww2 = w + pp; float p2 = fmaxf(ww2, kt);                \
    float e1b = __expf(ww2 - p2), e2b = __expf(kt - p2);          \
    aa = e1b * aa + e2b * vt; bb = e1b * bb + e2b; pp = p2;       \
  }

__global__ __launch_bounds__(256) void wkv_pass2(
    const unsigned short* __restrict__ Kin, const unsigned short* __restrict__ Vin,
    const int* __restrict__ sidx,
    const float* __restrict__ decay, const float* __restrict__ first,
    const float* __restrict__ aI, const float* __restrict__ bI,
    const float* __restrict__ pI, unsigned short* __restrict__ Y)
{
  __shared__ int si[CHL];
  const int tid = threadIdx.x;
  const int ch = blockIdx.x, b = blockIdx.z;
  const int c = blockIdx.y * 256 + tid;
  if (tid < CHL) si[tid] = sidx[ch * CHL + tid];
  __syncthreads();
  const float w = decay[c] * (1.0f / (float)T_SEQ);
  const float u = first[c] * (1.0f / (float)T_SEQ);
  const unsigned short* Kb = Kin + (size_t)b * T_SEQ * C_DIM + c;
  const unsigned short* Vb = Vin + (size_t)b * T_SEQ * C_DIM + c;
  unsigned short* Yb = Y + (size_t)b * T_SEQ * C_DIM + c;
  const int idx = (b * C_DIM + c) * NCH + ch;
  float aa = aI[idx], bb = bI[idx], pp = pI[idx];
  int rA[8], rB[8]; unsigned short kA[8], vA[8], kB[8], vB[8];
  P2_LOAD(rA, kA, vA, 0)
  for (int t0 = 0; t0 < CHL; t0 += 16) {
    P2_LOAD(rB, kB, vB, t0 + 8)
    P2_COMP(rA, kA, vA)
    if (t0 + 16 < CHL) { P2_LOAD(rA, kA, vA, t0 + 16) }
    P2_COMP(rB, kB, vB)
  }
}

// ---------------------------------------------------------------------------
// Row LayerNorm over C + sigmoid gate; bf16 in (Y, SR), bf16 out (G).
// ---------------------------------------------------------------------------
__global__ __launch_bounds__(256) void ln_gate(
    const unsigned short* __restrict__ Y, const unsigned short* __restrict__ SR,
    const float* __restrict__ gam, const float* __restrict__ bet,
    unsigned short* __restrict__ G)
{
  const size_t row = blockIdx.x;
  const unsigned short* x = Y + row * C_DIM;
  const unsigned short* sr = SR + row * C_DIM;
  unsigned short* go = G + row * C_DIM;
  const int tid = threadIdx.x;

  float vals[3];
  float s = 0.f, s2 = 0.f;
#pragma unroll
  for (int j = 0; j < 3; ++j) {
    float v = bf2f(x[tid + j * 256]);
    vals[j] = v;
    s += v; s2 += v * v;
  }
#pragma unroll
  for (int off = 32; off >= 1; off >>= 1) {
    s  += __shfl_xor(s, off, 64);
    s2 += __shfl_xor(s2, off, 64);
  }
  __shared__ float red[8];
  const int wid = tid >> 6;
  if ((tid & 63) == 0) { red[wid] = s; red[wid + 4] = s2; }
  __syncthreads();
  s  = red[0] + red[1] + red[2] + red[3];
  s2 = red[4] + red[5] + red[6] + red[7];

  const float mu   = s * (1.f / (float)C_DIM);
  const float var  = s2 * (1.f / (float)C_DIM) - mu * mu;
  const float rsig = rsqrtf(var + 1e-5f);

#pragma unroll
  for (int j = 0; j < 3; ++j) {
    const int cc = tid + j * 256;
    float yv = (vals[j] - mu) * rsig * gam[cc] + bet[cc];
    go[cc] = f2bf(yv * bf2f(sr[cc]));
  }
}

// ---------------------------------------------------------------------------
extern "C" void kernel_launch(void* const* d_in, const int* in_sizes, int n_in,
                              void* d_out, int out_size, void* d_ws, size_t ws_size,
                              hipStream_t stream) {
  const float* x     = (const float*)d_in[0];
  const int*   sidx  = (const int*)  d_in[1];
  const float* decay = (const float*)d_in[2];
  const float* first = (const float*)d_in[3];
  const float* Wk    = (const float*)d_in[4];
  const float* Wv    = (const float*)d_in[5];
  const float* Wr    = (const float*)d_in[6];
  const float* Wo    = (const float*)d_in[7];
  const float* ln_g  = (const float*)d_in[8];
  const float* ln_b  = (const float*)d_in[9];
  float* out = (float*)d_out;

  const size_t NE = (size_t)M_ROWS * C_DIM;  // 25165824
  // Workspace layout (~210 MB):
  short* Whs  = (short*)d_ws;                        // 4*CC bf16 [Wk|Wv|Wr|Wo]
  short* x_hi = Whs + 4 * (size_t)CC;                // NE bf16
  unsigned short* Ybuf = (unsigned short*)x_hi;      // alias: Y after kvr done
  unsigned short* Kbuf = (unsigned short*)(x_hi + NE);  // NE bf16
  unsigned short* Gbuf = Kbuf;                       // alias: after K dead
  unsigned short* Vbuf = Kbuf + NE;                  // NE bf16
  unsigned short* SRb  = Vbuf + NE;                  // NE bf16
  float* aL = (float*)(SRb + NE);                    // 6 x 196608 f32
  float* bL = aL + 196608;
  float* pL = bL + 196608;
  float* aI = pL + 196608;
  float* bI = aI + 196608;
  float* pI = bI + 196608;

  // Allow 128 KB dynamic LDS (idempotent, capture-safe).
  (void)hipFuncSetAttribute(reinterpret_cast<const void*>(&gemm8p<0>),
                            hipFuncAttributeMaxDynamicSharedMemorySize, 131072);
  (void)hipFuncSetAttribute(reinterpret_cast<const void*>(&gemm8p<1>),
                            hipFuncAttributeMaxDynamicSharedMemorySize, 131072);

  // 1) bf16 conversions
  convert_x<<<24576, 256, 0, stream>>>((const float4*)x, (ushort4*)x_hi);
  convert_w4<<<dim3(576, 4), 256, 0, stream>>>(
      (const float4*)Wk, (const float4*)Wv, (const float4*)Wr, (const float4*)Wo,
      (ushort4*)Whs);

  // 2) fused k|v|sr GEMM: M=32768, N=2304, K=768; all outputs bf16
  gemm8p<0><<<dim3(9, 128), 512, 131072, stream>>>(
      x_hi, Whs, Kbuf, Vbuf, SRb, nullptr);

  // 3) WKV: chunk transitions -> serial chunk scan -> replay with y output
  wkv_pass1<<<dim3(NCH, 3, B_DIM), 256, 0, stream>>>(Kbuf, Vbuf, sidx, decay, aL, bL, pL);
  wkv_scan<<<24, 256, 0, stream>>>(aL, bL, pL, aI, bI, pI, decay);
  wkv_pass2<<<dim3(NCH, 3, B_DIM), 256, 0, stream>>>(Kbuf, Vbuf, sidx, decay, first,
                                                     aI, bI, pI, Ybuf);
  // 4) LayerNorm + gate -> bf16 GEMM operand (G aliases K; K dead now)
  ln_gate<<<M_ROWS, 256, 0, stream>>>(Ybuf, SRb, ln_g, ln_b, Gbuf);
  // 5) out = G @ Wo^T (384 blocks of 256^2, f32 out)
  gemm8p<1><<<dim3(3, 128), 512, 131072, stream>>>(
      (const short*)Gbuf, Whs + 3 * (size_t)CC, nullptr, nullptr, nullptr, out);
}